// Round 7
// baseline (96.887 us; speedup 1.0000x reference)
//
#include <hip/hip_runtime.h>
#include <hip/hip_bf16.h>
#include <stdint.h>
#include <math.h>

// Problem constants
#define VOCAB 1000000
#define D 128
#define NROWS 16384
#define NSAMP 8192
#define SSPLIT 8                       // flash: S split across 8 block groups
#define NBLK (64 * SSPLIT)             // flash grid = 512 blocks
#define K1F 28.853900817779268f        // (1/TEMP)*log2(e) = 20*log2(e)
#define LOG2EF 1.4426950408889634f

// ws layout (bytes)
#define XF_OFF 0u                      // N*D bf16 = 4 MB, fragment-major, pre-scaled by K1F
#define EF_OFF 4194304u                // S*D bf16 = 2 MB, fragment-major
#define PL_OFF 6291456u                // pos_logit fp32 [N] = 64 KB
#define PS_OFF 6356992u                // psum fp32 [SSPLIT][N] = 512 KB
#define FP_OFF 6881280u                // fin partials [64][2] = 512 B
#define CNT_OFF 6882304u               // 2 counters (zeroed by prep each launch)

typedef __attribute__((ext_vector_type(8))) __bf16 bf16x8;
typedef __attribute__((ext_vector_type(16))) float f32x16;

#if __has_builtin(__builtin_amdgcn_exp2f)
#define EXP2(x) __builtin_amdgcn_exp2f(x)
#else
#define EXP2(x) exp2f(x)
#endif

__device__ __forceinline__ void gl_lds16(const void* g, void* l) {
  __builtin_amdgcn_global_load_lds(
      (const __attribute__((address_space(1))) unsigned int*)g,
      (__attribute__((address_space(3))) unsigned int*)l, 16, 0, 0);
}

__device__ __forceinline__ float wave_sum(float v) {
#pragma unroll
  for (int o = 1; o < 64; o <<= 1) v += __shfl_xor(v, o);
  return v;
}

// exp2 each of 16 fp32 and tree-sum (short dependent chains).
__device__ __forceinline__ float expsum16(const f32x16& c) {
  float e[16];
#pragma unroll
  for (int r = 0; r < 16; ++r) e[r] = EXP2(c[r]);
#pragma unroll
  for (int s = 8; s; s >>= 1)
#pragma unroll
    for (int r = 0; r < s; ++r) e[r] += e[r + s];
  return e[0];
}

// Merged prep: blocks [0,4096) handle X rows (normalize, pre-scale by K1F,
// fragment-major bf16 store, fp32 pos logit); blocks [4096,6144) handle E rows.
// Block 0 also zeroes the two fused-kernel counters (stream-ordered).
__global__ void prep_kernel(const float* __restrict__ x,
                            const int* __restrict__ tgt,
                            const int* __restrict__ nid,
                            const float* __restrict__ proj,
                            __bf16* __restrict__ xf,
                            __bf16* __restrict__ ef,
                            float* __restrict__ pl,
                            unsigned int* __restrict__ cnt) {
  if (blockIdx.x == 0 && threadIdx.x == 0) { cnt[0] = 0u; cnt[1] = 0u; }
  const int wave = threadIdx.x >> 6, lane = threadIdx.x & 63;
  const int d = lane * 2;
  const int kk = d >> 4, sub = (d & 15) >> 3, j = d & 7;
  if (blockIdx.x < 4096) {
    const int n = blockIdx.x * 4 + wave;
    const float2 xr = *reinterpret_cast<const float2*>(x + (size_t)n * D + lane * 2);
    const float rnx = 1.f / (sqrtf(wave_sum(xr.x * xr.x + xr.y * xr.y)) + 1e-12f);
    const int t = tgt[n];
    const int tg = t < 0 ? 0 : (t > VOCAB - 1 ? VOCAB - 1 : t);
    const float2 pr = *reinterpret_cast<const float2*>(proj + (size_t)tg * D + lane * 2);
    const float rnp = 1.f / (sqrtf(wave_sum(pr.x * pr.x + pr.y * pr.y)) + 1e-12f);
    const float dt = wave_sum(xr.x * pr.x + xr.y * pr.y);
    if (lane == 0) pl[n] = dt * rnx * rnp * 20.0f;  // /TEMP, exact fp32
    const int tile = n >> 5, lt = (sub << 5) | (n & 31);
    __bf16* dst = xf + ((((size_t)tile * 8 + kk) * 64 + lt) * 8 + j);
    const float s = rnx * K1F;  // fold logit scale (in log2 base) into X
    dst[0] = (__bf16)(xr.x * s);
    dst[1] = (__bf16)(xr.y * s);
  } else {
    const int s = (blockIdx.x - 4096) * 4 + wave;
    const int id = nid[s];
    const float2 er = *reinterpret_cast<const float2*>(proj + (size_t)id * D + lane * 2);
    const float rn = 1.f / (sqrtf(wave_sum(er.x * er.x + er.y * er.y)) + 1e-12f);
    const int tile = s >> 5, lt = (sub << 5) | (s & 31);
    __bf16* dst = ef + ((((size_t)tile * 8 + kk) * 64 + lt) * 8 + j);
    dst[0] = (__bf16)(er.x * rn);
    dst[1] = (__bf16)(er.y * rn);
  }
}

// Fused flash+finish+final. Flash part identical to R6 (F=2, 4 waves, 16
// supertiles, double-buffered global_load_lds). After psum publish, ss==0
// blocks wait for all 512 blocks (agent-scope counter) and run finish for
// their own 256 rows; last of the 64 reduces to out[0]. Deadlock-free:
// (256,3) guarantees >=3 blocks/CU -> all 512 blocks co-resident.
__global__ __launch_bounds__(256, 3) void flash_kernel(
    const __bf16* __restrict__ xf, const __bf16* __restrict__ ef,
    const float* __restrict__ pl, const int* __restrict__ tgt,
    const float* __restrict__ wts, float* __restrict__ psum,
    float* __restrict__ fin, unsigned int* __restrict__ cnt,
    float* __restrict__ out) {
  __shared__ __align__(16) char lds[2][16384];
  const int tid = threadIdx.x, wave = tid >> 6, lane = tid & 63;
  const int nb = blockIdx.x & 63, ss = blockIdx.x >> 6;

  // B fragments (X): 2 n-frags (64 rows) x 8 k-steps, from frag-major xf.
  bf16x8 bq[2][8];
#pragma unroll
  for (int nf = 0; nf < 2; ++nf) {
    const __bf16* p = xf + ((size_t)(nb * 8 + wave * 2 + nf) * 4096) + lane * 8;
#pragma unroll
    for (int kk = 0; kk < 8; ++kk)
      bq[nf][kk] = *reinterpret_cast<const bf16x8*>(p + kk * 512);
  }

  const char* esrc = reinterpret_cast<const char*>(ef) + (size_t)ss * 262144;
  float acc0 = 0.f, acc1 = 0.f;

  {  // stage supertile 0 (4 waves x 4 chunks of 1 KB each)
    const char* g = esrc + wave * 1024 + lane * 16;
    char* l = &lds[0][0] + wave * 1024;
#pragma unroll
    for (int i = 0; i < 4; ++i) gl_lds16(g + i * 4096, l + i * 4096);
  }
  __syncthreads();

  for (int st = 0; st < 16; ++st) {
    if (st < 15) {  // prefetch next supertile into the other buffer
      const char* g = esrc + (size_t)(st + 1) * 16384 + wave * 1024 + lane * 16;
      char* l = &lds[(st + 1) & 1][0] + wave * 1024;
#pragma unroll
      for (int i = 0; i < 4; ++i) gl_lds16(g + i * 4096, l + i * 4096);
    }
    const char* cb = &lds[st & 1][0];
#pragma unroll
    for (int tt = 0; tt < 2; ++tt) {
      f32x16 c0, c1;
#pragma unroll
      for (int r = 0; r < 16; ++r) { c0[r] = 0.f; c1[r] = 0.f; }
      const char* ab = cb + tt * 8192 + lane * 16;
#pragma unroll
      for (int kk = 0; kk < 8; ++kk) {
        bf16x8 a = *reinterpret_cast<const bf16x8*>(ab + kk * 1024);
        c0 = __builtin_amdgcn_mfma_f32_32x32x16_bf16(a, bq[0][kk], c0, 0, 0, 0);
        c1 = __builtin_amdgcn_mfma_f32_32x32x16_bf16(a, bq[1][kk], c1, 0, 0, 0);
      }
      acc0 += expsum16(c0);
      acc1 += expsum16(c1);
    }
    __syncthreads();
  }

  // Publish psum (lanes l and l+32 hold different s-rows of same column n).
  acc0 += __shfl_xor(acc0, 32);
  acc1 += __shfl_xor(acc1, 32);
  if (lane < 32) {
    const int nbase = nb * 256 + wave * 64;
    __hip_atomic_store(&psum[(size_t)ss * NROWS + nbase + lane], acc0,
                       __ATOMIC_RELAXED, __HIP_MEMORY_SCOPE_AGENT);
    __hip_atomic_store(&psum[(size_t)ss * NROWS + nbase + 32 + lane], acc1,
                       __ATOMIC_RELAXED, __HIP_MEMORY_SCOPE_AGENT);
  }
  __threadfence();
  __syncthreads();
  if (threadIdx.x == 0)
    __hip_atomic_fetch_add(&cnt[0], 1u, __ATOMIC_ACQ_REL,
                           __HIP_MEMORY_SCOPE_AGENT);
  if (ss != 0) return;

  // ---- finish phase: ss==0 blocks own rows [nb*256, nb*256+256) ----
  if (threadIdx.x == 0) {
    while (__hip_atomic_load(&cnt[0], __ATOMIC_ACQUIRE,
                             __HIP_MEMORY_SCOPE_AGENT) < (unsigned)NBLK)
      __builtin_amdgcn_s_sleep(2);
  }
  __syncthreads();
  __threadfence();

  const int row = nb * 256 + threadIdx.x;
  float tot = 0.f;
#pragma unroll
  for (int s = 0; s < SSPLIT; ++s)
    tot += __hip_atomic_load(&psum[(size_t)s * NROWS + row], __ATOMIC_RELAXED,
                             __HIP_MEMORY_SCOPE_AGENT);
  const float p = pl[row];
  tot += EXP2(p * LOG2EF);             // + exp(pos_logit), unshifted
  const float ce = logf(tot) - p;      // logZ - pos_logit
  const float w = wts[row] * (tgt[row] != -100 ? 1.f : 0.f);
  float a = wave_sum(ce * w);
  float b = wave_sum(w);
  __shared__ float sa[4], sb[4];
  __shared__ int last;
  if (lane == 0) { sa[wave] = a; sb[wave] = b; }
  __syncthreads();
  if (threadIdx.x == 0) {
    __hip_atomic_store(&fin[nb * 2], sa[0] + sa[1] + sa[2] + sa[3],
                       __ATOMIC_RELAXED, __HIP_MEMORY_SCOPE_AGENT);
    __hip_atomic_store(&fin[nb * 2 + 1], sb[0] + sb[1] + sb[2] + sb[3],
                       __ATOMIC_RELAXED, __HIP_MEMORY_SCOPE_AGENT);
    const unsigned int o2 = __hip_atomic_fetch_add(&cnt[1], 1u, __ATOMIC_ACQ_REL,
                                                   __HIP_MEMORY_SCOPE_AGENT);
    last = (o2 == 63u);
  }
  __syncthreads();
  if (last && threadIdx.x < 64) {  // wave 0 reduces the 64 fin pairs
    const float A = wave_sum(__hip_atomic_load(&fin[threadIdx.x * 2],
                                               __ATOMIC_RELAXED,
                                               __HIP_MEMORY_SCOPE_AGENT));
    const float B = wave_sum(__hip_atomic_load(&fin[threadIdx.x * 2 + 1],
                                               __ATOMIC_RELAXED,
                                               __HIP_MEMORY_SCOPE_AGENT));
    if (threadIdx.x == 0) out[0] = A / fmaxf(B, 1e-12f);
  }
}

extern "C" void kernel_launch(void* const* d_in, const int* in_sizes, int n_in,
                              void* d_out, int out_size, void* d_ws, size_t ws_size,
                              hipStream_t stream) {
  const float* x    = (const float*)d_in[0];
  const int*   tgt  = (const int*)d_in[1];
  const int*   nid  = (const int*)d_in[2];
  const float* wts  = (const float*)d_in[3];
  const float* proj = (const float*)d_in[4];
  float* out = (float*)d_out;
  char* ws = (char*)d_ws;
  __bf16* xf = (__bf16*)(ws + XF_OFF);
  __bf16* ef = (__bf16*)(ws + EF_OFF);
  float* pl   = (float*)(ws + PL_OFF);
  float* psum = (float*)(ws + PS_OFF);
  float* fin  = (float*)(ws + FP_OFF);
  unsigned int* cnt = (unsigned int*)(ws + CNT_OFF);

  hipLaunchKernelGGL(prep_kernel, dim3(4096 + 2048), dim3(256), 0, stream,
                     x, tgt, nid, proj, xf, ef, pl, cnt);
  hipLaunchKernelGGL(flash_kernel, dim3(NBLK), dim3(256), 0, stream,
                     xf, ef, pl, tgt, wts, psum, fin, cnt, out);
}

// Round 8
// 49.357 us; speedup vs baseline: 1.9630x; 1.9630x over previous
//
#include <hip/hip_runtime.h>
#include <hip/hip_bf16.h>
#include <stdint.h>
#include <math.h>

// Problem constants
#define VOCAB 1000000
#define D 128
#define NROWS 16384
#define NSAMP 8192
#define SSPLIT 8                       // flash: S split across 8 block groups
#define K1F 28.853900817779268f        // (1/TEMP)*log2(e) = 20*log2(e)
#define LOG2EF 1.4426950408889634f

// ws layout (bytes)
#define XF_OFF 0u                      // N*D bf16 = 4 MB, fragment-major, pre-scaled by K1F
#define EF_OFF 4194304u                // S*D bf16 = 2 MB, fragment-major
#define PL_OFF 6291456u                // pos_logit fp32 [N] = 64 KB
#define PS_OFF 6356992u                // psum fp32 [SSPLIT][N] = 512 KB
#define FP_OFF 6881280u                // fin partials [64][2] = 512 B
#define CNT_OFF 6882304u               // counter (zeroed by prep each launch)

typedef __attribute__((ext_vector_type(8))) __bf16 bf16x8;
typedef __attribute__((ext_vector_type(16))) float f32x16;

#if __has_builtin(__builtin_amdgcn_exp2f)
#define EXP2(x) __builtin_amdgcn_exp2f(x)
#else
#define EXP2(x) exp2f(x)
#endif

__device__ __forceinline__ void gl_lds16(const void* g, void* l) {
  __builtin_amdgcn_global_load_lds(
      (const __attribute__((address_space(1))) unsigned int*)g,
      (__attribute__((address_space(3))) unsigned int*)l, 16, 0, 0);
}

__device__ __forceinline__ float wave_sum(float v) {
#pragma unroll
  for (int o = 1; o < 64; o <<= 1) v += __shfl_xor(v, o);
  return v;
}

// exp2 each of 16 fp32 and tree-sum (short dependent chains).
__device__ __forceinline__ float expsum16(const f32x16& c) {
  float e[16];
#pragma unroll
  for (int r = 0; r < 16; ++r) e[r] = EXP2(c[r]);
#pragma unroll
  for (int s = 8; s; s >>= 1)
#pragma unroll
    for (int r = 0; r < s; ++r) e[r] += e[r + s];
  return e[0];
}

// Store one row's float2 (dims d=lane*2) into fragment-major layout.
__device__ __forceinline__ void store_frag(__bf16* __restrict__ base, int row,
                                           int lane, float vx, float vy) {
  const int d = lane * 2;
  const int kk = d >> 4, sub = (d & 15) >> 3, j = d & 7;
  const int tile = row >> 5, lt = (sub << 5) | (row & 31);
  __bf16* dst = base + ((((size_t)tile * 8 + kk) * 64 + lt) * 8 + j);
  dst[0] = (__bf16)vx;
  dst[1] = (__bf16)vy;
}

// Prep with 4-row-per-wave ILP: all independent HBM gathers issued before any
// reduction so the two ~900ns gather latencies overlap within the wave.
// Blocks [0,1024): X rows (16/block). Blocks [1024,1536): E rows (16/block).
// Block 0 zeroes the finish counter (stream-ordered before finish_kernel).
__global__ __launch_bounds__(256) void prep_kernel(
    const float* __restrict__ x, const int* __restrict__ tgt,
    const int* __restrict__ nid, const float* __restrict__ proj,
    __bf16* __restrict__ xf, __bf16* __restrict__ ef,
    float* __restrict__ pl, unsigned int* __restrict__ cnt) {
  if (blockIdx.x == 0 && threadIdx.x == 0) *cnt = 0u;
  const int wave = threadIdx.x >> 6, lane = threadIdx.x & 63;
  if (blockIdx.x < 1024) {
    const int n0 = blockIdx.x * 16 + wave * 4;
    int tg[4];
    float2 xr[4], pr[4];
#pragma unroll
    for (int i = 0; i < 4; ++i) {
      const int t = tgt[n0 + i];
      tg[i] = t < 0 ? 0 : (t > VOCAB - 1 ? VOCAB - 1 : t);
      xr[i] = *reinterpret_cast<const float2*>(x + (size_t)(n0 + i) * D + lane * 2);
    }
#pragma unroll
    for (int i = 0; i < 4; ++i)
      pr[i] = *reinterpret_cast<const float2*>(proj + (size_t)tg[i] * D + lane * 2);
#pragma unroll
    for (int i = 0; i < 4; ++i) {
      float sx = xr[i].x * xr[i].x + xr[i].y * xr[i].y;
      float sp = pr[i].x * pr[i].x + pr[i].y * pr[i].y;
      float dt = xr[i].x * pr[i].x + xr[i].y * pr[i].y;
#pragma unroll
      for (int o = 1; o < 64; o <<= 1) {
        sx += __shfl_xor(sx, o);
        sp += __shfl_xor(sp, o);
        dt += __shfl_xor(dt, o);
      }
      const float rnx = 1.f / (sqrtf(sx) + 1e-12f);
      if (lane == 0)
        pl[n0 + i] = dt * rnx * (1.f / (sqrtf(sp) + 1e-12f)) * 20.0f;  // /TEMP
      const float sc = rnx * K1F;  // fold logit scale (log2 base) into X
      store_frag(xf, n0 + i, lane, xr[i].x * sc, xr[i].y * sc);
    }
  } else {
    const int s0 = (blockIdx.x - 1024) * 16 + wave * 4;
    float2 er[4];
#pragma unroll
    for (int i = 0; i < 4; ++i) {
      const int id = nid[s0 + i];
      er[i] = *reinterpret_cast<const float2*>(proj + (size_t)id * D + lane * 2);
    }
#pragma unroll
    for (int i = 0; i < 4; ++i) {
      const float rn =
          1.f / (sqrtf(wave_sum(er[i].x * er[i].x + er[i].y * er[i].y)) + 1e-12f);
      store_frag(ef, s0 + i, lane, er[i].x * rn, er[i].y * rn);
    }
  }
}

// Flash kernel, F=2 (byte-identical compute to R6): block = 4 waves x 2
// n-frags (256 X-cols), 16 64-s supertiles, double-buffered global_load_lds.
__global__ __launch_bounds__(256, 3) void flash_kernel(
    const __bf16* __restrict__ xf, const __bf16* __restrict__ ef,
    float* __restrict__ psum) {
  __shared__ __align__(16) char lds[2][16384];
  const int tid = threadIdx.x, wave = tid >> 6, lane = tid & 63;
  const int nb = blockIdx.x & 63, ss = blockIdx.x >> 6;

  // B fragments (X): 2 n-frags (64 rows) x 8 k-steps, from frag-major xf.
  bf16x8 bq[2][8];
#pragma unroll
  for (int nf = 0; nf < 2; ++nf) {
    const __bf16* p = xf + ((size_t)(nb * 8 + wave * 2 + nf) * 4096) + lane * 8;
#pragma unroll
    for (int kk = 0; kk < 8; ++kk)
      bq[nf][kk] = *reinterpret_cast<const bf16x8*>(p + kk * 512);
  }

  const char* esrc = reinterpret_cast<const char*>(ef) + (size_t)ss * 262144;
  float acc0 = 0.f, acc1 = 0.f;

  {  // stage supertile 0 (4 waves x 4 chunks of 1 KB each)
    const char* g = esrc + wave * 1024 + lane * 16;
    char* l = &lds[0][0] + wave * 1024;
#pragma unroll
    for (int i = 0; i < 4; ++i) gl_lds16(g + i * 4096, l + i * 4096);
  }
  __syncthreads();

  for (int st = 0; st < 16; ++st) {
    if (st < 15) {  // prefetch next supertile into the other buffer
      const char* g = esrc + (size_t)(st + 1) * 16384 + wave * 1024 + lane * 16;
      char* l = &lds[(st + 1) & 1][0] + wave * 1024;
#pragma unroll
      for (int i = 0; i < 4; ++i) gl_lds16(g + i * 4096, l + i * 4096);
    }
    const char* cb = &lds[st & 1][0];
#pragma unroll
    for (int tt = 0; tt < 2; ++tt) {
      f32x16 c0, c1;
#pragma unroll
      for (int r = 0; r < 16; ++r) { c0[r] = 0.f; c1[r] = 0.f; }
      const char* ab = cb + tt * 8192 + lane * 16;
#pragma unroll
      for (int kk = 0; kk < 8; ++kk) {
        bf16x8 a = *reinterpret_cast<const bf16x8*>(ab + kk * 1024);
        c0 = __builtin_amdgcn_mfma_f32_32x32x16_bf16(a, bq[0][kk], c0, 0, 0, 0);
        c1 = __builtin_amdgcn_mfma_f32_32x32x16_bf16(a, bq[1][kk], c1, 0, 0, 0);
      }
      acc0 += expsum16(c0);
      acc1 += expsum16(c1);
    }
    __syncthreads();
  }

  // lanes l and l+32 hold different s-rows of the same column n: combine.
  acc0 += __shfl_xor(acc0, 32);
  acc1 += __shfl_xor(acc1, 32);
  if (lane < 32) {
    const int nbase = nb * 256 + wave * 64;
    psum[(size_t)ss * NROWS + nbase + lane] = acc0;
    psum[(size_t)ss * NROWS + nbase + 32 + lane] = acc1;
  }
}

// Finish (with fused final): 64 blocks x 256 rows. Per-row CE + weighted
// partials; the last-arriving block (64 ACQ_REL bumps total — cheap) reduces
// the 64 fin pairs and writes out[0]. Deterministic fixed-order reductions.
__global__ __launch_bounds__(256) void finish_kernel(
    const float* __restrict__ psum, const float* __restrict__ pl,
    const int* __restrict__ tgt, const float* __restrict__ wts,
    float* __restrict__ fin, unsigned int* __restrict__ cnt,
    float* __restrict__ out) {
  const int n = blockIdx.x * 256 + threadIdx.x;
  float tot = 0.f;
#pragma unroll
  for (int s = 0; s < SSPLIT; ++s) tot += psum[(size_t)s * NROWS + n];
  const float p = pl[n];
  tot += EXP2(p * LOG2EF);             // + exp(pos_logit), unshifted
  const float ce = logf(tot) - p;      // logZ - pos_logit
  const float w = wts[n] * (tgt[n] != -100 ? 1.f : 0.f);
  float a = wave_sum(ce * w);
  float b = wave_sum(w);
  __shared__ float sa[4], sb[4];
  __shared__ int last;
  const int wave = threadIdx.x >> 6, lane = threadIdx.x & 63;
  if (lane == 0) { sa[wave] = a; sb[wave] = b; }
  __syncthreads();
  if (threadIdx.x == 0) {
    __hip_atomic_store(&fin[blockIdx.x * 2], sa[0] + sa[1] + sa[2] + sa[3],
                       __ATOMIC_RELAXED, __HIP_MEMORY_SCOPE_AGENT);
    __hip_atomic_store(&fin[blockIdx.x * 2 + 1], sb[0] + sb[1] + sb[2] + sb[3],
                       __ATOMIC_RELAXED, __HIP_MEMORY_SCOPE_AGENT);
    const unsigned int old = __hip_atomic_fetch_add(cnt, 1u, __ATOMIC_ACQ_REL,
                                                    __HIP_MEMORY_SCOPE_AGENT);
    last = (old == 63u);
  }
  __syncthreads();
  if (last && threadIdx.x < 64) {  // wave 0 of last block reduces 64 pairs
    const float A = wave_sum(__hip_atomic_load(&fin[threadIdx.x * 2],
                                               __ATOMIC_RELAXED,
                                               __HIP_MEMORY_SCOPE_AGENT));
    const float B = wave_sum(__hip_atomic_load(&fin[threadIdx.x * 2 + 1],
                                               __ATOMIC_RELAXED,
                                               __HIP_MEMORY_SCOPE_AGENT));
    if (threadIdx.x == 0) out[0] = A / fmaxf(B, 1e-12f);
  }
}

extern "C" void kernel_launch(void* const* d_in, const int* in_sizes, int n_in,
                              void* d_out, int out_size, void* d_ws, size_t ws_size,
                              hipStream_t stream) {
  const float* x    = (const float*)d_in[0];
  const int*   tgt  = (const int*)d_in[1];
  const int*   nid  = (const int*)d_in[2];
  const float* wts  = (const float*)d_in[3];
  const float* proj = (const float*)d_in[4];
  float* out = (float*)d_out;
  char* ws = (char*)d_ws;
  __bf16* xf = (__bf16*)(ws + XF_OFF);
  __bf16* ef = (__bf16*)(ws + EF_OFF);
  float* pl   = (float*)(ws + PL_OFF);
  float* psum = (float*)(ws + PS_OFF);
  float* fin  = (float*)(ws + FP_OFF);
  unsigned int* cnt = (unsigned int*)(ws + CNT_OFF);

  hipLaunchKernelGGL(prep_kernel, dim3(1024 + 512), dim3(256), 0, stream,
                     x, tgt, nid, proj, xf, ef, pl, cnt);
  hipLaunchKernelGGL(flash_kernel, dim3(64 * SSPLIT), dim3(256), 0, stream,
                     xf, ef, psum);
  hipLaunchKernelGGL(finish_kernel, dim3(NROWS / 256), dim3(256), 0, stream,
                     psum, pl, tgt, wts, fin, cnt, out);
}

// Round 9
// 42.724 us; speedup vs baseline: 2.2677x; 1.1553x over previous
//
#include <hip/hip_runtime.h>
#include <hip/hip_bf16.h>
#include <stdint.h>
#include <math.h>

// Problem constants
#define VOCAB 1000000
#define D 128
#define NROWS 16384
#define NSAMP 8192
#define SSPLIT 8                       // flash: S split across 8 block groups
#define K1F 28.853900817779268f        // (1/TEMP)*log2(e) = 20*log2(e)
#define LOG2EF 1.4426950408889634f

// ws layout (bytes) — i8 fragment-major buffers
#define XF_OFF 0u                      // N*D i8 = 2 MB, frag-major, per-row qscale
#define EF_OFF 2097152u                // S*D i8 = 1 MB, frag-major, fixed scale 127
#define PL_OFF 3145728u                // pos_logit fp32 [N] = 64 KB
#define SCX_OFF 3211264u               // per-row exp-arg scale fp32 [N] = 64 KB
#define PS_OFF 3276800u                // psum fp32 [SSPLIT][N] = 512 KB
#define FP_OFF 3801088u                // fin partials [64][2] = 512 B
#define CNT_OFF 3802112u               // counter (zeroed by prep each launch)

typedef __attribute__((ext_vector_type(4))) int i32x4;
typedef __attribute__((ext_vector_type(16))) int i32x16;

#if __has_builtin(__builtin_amdgcn_exp2f)
#define EXP2(x) __builtin_amdgcn_exp2f(x)
#else
#define EXP2(x) exp2f(x)
#endif

__device__ __forceinline__ void gl_lds16(const void* g, void* l) {
  __builtin_amdgcn_global_load_lds(
      (const __attribute__((address_space(1))) unsigned int*)g,
      (__attribute__((address_space(3))) unsigned int*)l, 16, 0, 0);
}

__device__ __forceinline__ float wave_sum(float v) {
#pragma unroll
  for (int o = 1; o < 64; o <<= 1) v += __shfl_xor(v, o);
  return v;
}

// Store one row's 2 consecutive dims (d = lane*2) as i8 into frag-major:
// element (row, d): kk = d>>5 (K-step of 32), sub = (d&31)>>4, j = d&15,
// byte = ((tile*4 + kk)*64 + ((sub<<5)|(row&31)))*16 + j.
__device__ __forceinline__ void store_frag_i8(char* __restrict__ base, int row,
                                              int lane, int bx, int by) {
  const int d = lane * 2;
  const int kk = d >> 5, sub = (d & 31) >> 4, j = d & 15;
  const int tile = row >> 5, lt = (sub << 5) | (row & 31);
  char* dst = base + (((size_t)(tile * 4 + kk) * 64 + lt) * 16 + j);
  dst[0] = (char)bx;
  dst[1] = (char)by;
}

// Prep: X rows -> i8 frag-major (per-row qscale=127/rawmax), scx[n] exp-arg
// scale, exact fp32 pos logit; E rows -> i8 frag-major (normalized, scale 127).
// 4 rows/wave with gathers issued up front (latency ILP). Block 0 zeroes cnt.
__global__ __launch_bounds__(256) void prep_kernel(
    const float* __restrict__ x, const int* __restrict__ tgt,
    const int* __restrict__ nid, const float* __restrict__ proj,
    char* __restrict__ xf, char* __restrict__ ef,
    float* __restrict__ pl, float* __restrict__ scx,
    unsigned int* __restrict__ cnt) {
  if (blockIdx.x == 0 && threadIdx.x == 0) *cnt = 0u;
  const int wave = threadIdx.x >> 6, lane = threadIdx.x & 63;
  if (blockIdx.x < 1024) {
    const int n0 = blockIdx.x * 16 + wave * 4;
    int tg[4];
    float2 xr[4], pr[4];
#pragma unroll
    for (int i = 0; i < 4; ++i) {
      const int t = tgt[n0 + i];
      tg[i] = t < 0 ? 0 : (t > VOCAB - 1 ? VOCAB - 1 : t);
      xr[i] = *reinterpret_cast<const float2*>(x + (size_t)(n0 + i) * D + lane * 2);
    }
#pragma unroll
    for (int i = 0; i < 4; ++i)
      pr[i] = *reinterpret_cast<const float2*>(proj + (size_t)tg[i] * D + lane * 2);
#pragma unroll
    for (int i = 0; i < 4; ++i) {
      float sx = xr[i].x * xr[i].x + xr[i].y * xr[i].y;
      float sp = pr[i].x * pr[i].x + pr[i].y * pr[i].y;
      float dt = xr[i].x * pr[i].x + xr[i].y * pr[i].y;
      float mx = fmaxf(fabsf(xr[i].x), fabsf(xr[i].y));
#pragma unroll
      for (int o = 1; o < 64; o <<= 1) {
        sx += __shfl_xor(sx, o);
        sp += __shfl_xor(sp, o);
        dt += __shfl_xor(dt, o);
        mx = fmaxf(mx, __shfl_xor(mx, o));
      }
      const float norm = sqrtf(sx) + 1e-12f;
      if (lane == 0) {
        pl[n0 + i] = dt / (norm * (sqrtf(sp) + 1e-12f)) * 20.0f;  // /TEMP
        scx[n0 + i] = K1F * (mx + 1e-20f) / (16129.0f * norm);    // 127^2
      }
      const float qs = 127.0f / (mx + 1e-20f);  // raw-domain quant scale
      store_frag_i8(xf, n0 + i, lane, (int)rintf(xr[i].x * qs),
                    (int)rintf(xr[i].y * qs));
    }
  } else {
    const int s0 = (blockIdx.x - 1024) * 16 + wave * 4;
    float2 er[4];
#pragma unroll
    for (int i = 0; i < 4; ++i) {
      const int id = nid[s0 + i];
      er[i] = *reinterpret_cast<const float2*>(proj + (size_t)id * D + lane * 2);
    }
#pragma unroll
    for (int i = 0; i < 4; ++i) {
      const float qs =
          127.0f / (sqrtf(wave_sum(er[i].x * er[i].x + er[i].y * er[i].y)) + 1e-12f);
      store_frag_i8(ef, s0 + i, lane, (int)rintf(er[i].x * qs),
                    (int)rintf(er[i].y * qs));
    }
  }
}

// Flash kernel, i8 F=2: block = 4 waves x 2 n-frags (256 X-cols), 16 64-s
// supertiles of 8 KB (double-buffered global_load_lds). 4 MFMAs (K=32) per
// 32x32 tile; exact i32 accum; arg = c * scx[col]; psum = sum_s exp2(arg).
__global__ __launch_bounds__(256, 4) void flash_kernel(
    const char* __restrict__ xf, const char* __restrict__ ef,
    const float* __restrict__ scx, float* __restrict__ psum) {
  __shared__ __align__(16) char lds[2][8192];
  const int tid = threadIdx.x, wave = tid >> 6, lane = tid & 63;
  const int nb = blockIdx.x & 63, ss = blockIdx.x >> 6;
  const int nbase = nb * 256 + wave * 64;

  // B fragments (X): 2 n-frags (64 rows) x 4 k-steps, from frag-major xf.
  i32x4 bq[2][4];
#pragma unroll
  for (int nf = 0; nf < 2; ++nf) {
    const char* p = xf + ((size_t)(nb * 8 + wave * 2 + nf) * 4096) + lane * 16;
#pragma unroll
    for (int kk = 0; kk < 4; ++kk)
      bq[nf][kk] = *reinterpret_cast<const i32x4*>(p + kk * 1024);
  }
  const float scx0 = scx[nbase + (lane & 31)];
  const float scx1 = scx[nbase + 32 + (lane & 31)];

  const char* esrc = ef + (size_t)ss * 131072;  // 1024-s slice, 128 B/row
  float acc0 = 0.f, acc1 = 0.f;

  {  // stage supertile 0 (8 KB: 256 threads x 2 x 16 B)
    const char* g = esrc + tid * 16;
    char* l = &lds[0][0] + tid * 16;
    gl_lds16(g, l);
    gl_lds16(g + 4096, l + 4096);
  }
  __syncthreads();

  for (int st = 0; st < 16; ++st) {
    if (st < 15) {  // prefetch next supertile into the other buffer
      const char* g = esrc + (size_t)(st + 1) * 8192 + tid * 16;
      char* l = &lds[(st + 1) & 1][0] + tid * 16;
      gl_lds16(g, l);
      gl_lds16(g + 4096, l + 4096);
    }
    const char* cb = &lds[st & 1][0];
#pragma unroll
    for (int tt = 0; tt < 2; ++tt) {
      i32x16 c0, c1;
#pragma unroll
      for (int r = 0; r < 16; ++r) { c0[r] = 0; c1[r] = 0; }
      const char* ab = cb + tt * 4096 + lane * 16;
#pragma unroll
      for (int kk = 0; kk < 4; ++kk) {
        i32x4 a = *reinterpret_cast<const i32x4*>(ab + kk * 1024);
        c0 = __builtin_amdgcn_mfma_i32_32x32x32_i8(a, bq[0][kk], c0, 0, 0, 0);
        c1 = __builtin_amdgcn_mfma_i32_32x32x32_i8(a, bq[1][kk], c1, 0, 0, 0);
      }
      float e0[16], e1[16];
#pragma unroll
      for (int r = 0; r < 16; ++r) {
        e0[r] = EXP2((float)c0[r] * scx0);
        e1[r] = EXP2((float)c1[r] * scx1);
      }
#pragma unroll
      for (int s2 = 8; s2; s2 >>= 1)
#pragma unroll
        for (int r = 0; r < s2; ++r) { e0[r] += e0[r + s2]; e1[r] += e1[r + s2]; }
      acc0 += e0[0];
      acc1 += e1[0];
    }
    __syncthreads();
  }

  // lanes l and l+32 hold different s-rows of the same column n: combine.
  acc0 += __shfl_xor(acc0, 32);
  acc1 += __shfl_xor(acc1, 32);
  if (lane < 32) {
    psum[(size_t)ss * NROWS + nbase + lane] = acc0;
    psum[(size_t)ss * NROWS + nbase + 32 + lane] = acc1;
  }
}

// Finish (with fused final): 64 blocks x 256 rows. Per-row CE + weighted
// partials; last-arriving block (64 ACQ_REL bumps total) reduces to out[0].
__global__ __launch_bounds__(256) void finish_kernel(
    const float* __restrict__ psum, const float* __restrict__ pl,
    const int* __restrict__ tgt, const float* __restrict__ wts,
    float* __restrict__ fin, unsigned int* __restrict__ cnt,
    float* __restrict__ out) {
  const int n = blockIdx.x * 256 + threadIdx.x;
  float tot = 0.f;
#pragma unroll
  for (int s = 0; s < SSPLIT; ++s) tot += psum[(size_t)s * NROWS + n];
  const float p = pl[n];
  tot += EXP2(p * LOG2EF);             // + exp(pos_logit), unshifted
  const float ce = logf(tot) - p;      // logZ - pos_logit
  const float w = wts[n] * (tgt[n] != -100 ? 1.f : 0.f);
  float a = wave_sum(ce * w);
  float b = wave_sum(w);
  __shared__ float sa[4], sb[4];
  __shared__ int last;
  const int wave = threadIdx.x >> 6, lane = threadIdx.x & 63;
  if (lane == 0) { sa[wave] = a; sb[wave] = b; }
  __syncthreads();
  if (threadIdx.x == 0) {
    __hip_atomic_store(&fin[blockIdx.x * 2], sa[0] + sa[1] + sa[2] + sa[3],
                       __ATOMIC_RELAXED, __HIP_MEMORY_SCOPE_AGENT);
    __hip_atomic_store(&fin[blockIdx.x * 2 + 1], sb[0] + sb[1] + sb[2] + sb[3],
                       __ATOMIC_RELAXED, __HIP_MEMORY_SCOPE_AGENT);
    const unsigned int old = __hip_atomic_fetch_add(cnt, 1u, __ATOMIC_ACQ_REL,
                                                    __HIP_MEMORY_SCOPE_AGENT);
    last = (old == 63u);
  }
  __syncthreads();
  if (last && threadIdx.x < 64) {  // wave 0 of last block reduces 64 pairs
    const float A = wave_sum(__hip_atomic_load(&fin[threadIdx.x * 2],
                                               __ATOMIC_RELAXED,
                                               __HIP_MEMORY_SCOPE_AGENT));
    const float B = wave_sum(__hip_atomic_load(&fin[threadIdx.x * 2 + 1],
                                               __ATOMIC_RELAXED,
                                               __HIP_MEMORY_SCOPE_AGENT));
    if (threadIdx.x == 0) out[0] = A / fmaxf(B, 1e-12f);
  }
}

extern "C" void kernel_launch(void* const* d_in, const int* in_sizes, int n_in,
                              void* d_out, int out_size, void* d_ws, size_t ws_size,
                              hipStream_t stream) {
  const float* x    = (const float*)d_in[0];
  const int*   tgt  = (const int*)d_in[1];
  const int*   nid  = (const int*)d_in[2];
  const float* wts  = (const float*)d_in[3];
  const float* proj = (const float*)d_in[4];
  float* out = (float*)d_out;
  char* ws = (char*)d_ws;
  char* xf = ws + XF_OFF;
  char* ef = ws + EF_OFF;
  float* pl   = (float*)(ws + PL_OFF);
  float* scx  = (float*)(ws + SCX_OFF);
  float* psum = (float*)(ws + PS_OFF);
  float* fin  = (float*)(ws + FP_OFF);
  unsigned int* cnt = (unsigned int*)(ws + CNT_OFF);

  hipLaunchKernelGGL(prep_kernel, dim3(1024 + 512), dim3(256), 0, stream,
                     x, tgt, nid, proj, xf, ef, pl, scx, cnt);
  hipLaunchKernelGGL(flash_kernel, dim3(64 * SSPLIT), dim3(256), 0, stream,
                     xf, ef, scx, psum);
  hipLaunchKernelGGL(finish_kernel, dim3(NROWS / 256), dim3(256), 0, stream,
                     psum, pl, tgt, wts, fin, cnt, out);
}

// Round 10
// 42.121 us; speedup vs baseline: 2.3002x; 1.0143x over previous
//
#include <hip/hip_runtime.h>
#include <hip/hip_bf16.h>
#include <stdint.h>
#include <math.h>

// Problem constants
#define VOCAB 1000000
#define D 128
#define NROWS 16384
#define NSAMP 8192
#define SSPLIT 16                      // flash: S split across 16 block groups
#define K1F 28.853900817779268f        // (1/TEMP)*log2(e) = 20*log2(e)
#define LOG2EF 1.4426950408889634f

// ws layout (bytes) — i8 fragment-major buffers
#define XF_OFF 0u                      // N*D i8 = 2 MB, frag-major, per-row qscale
#define EF_OFF 2097152u                // S*D i8 = 1 MB, frag-major, scale 127
#define PL_OFF 3145728u                // pos_logit fp32 [N] = 64 KB
#define SCX_OFF 3211264u               // per-row exp-arg scale fp32 [N] = 64 KB
#define PS_OFF 3276800u                // psum fp32 [SSPLIT][N] = 1 MB
#define FP_OFF 4325376u                // fin partials [64][2] = 512 B
#define CNT_OFF 4326400u               // counter (zeroed by prep each launch)

typedef __attribute__((ext_vector_type(4))) int i32x4;
typedef __attribute__((ext_vector_type(16))) int i32x16;

#if __has_builtin(__builtin_amdgcn_exp2f)
#define EXP2(x) __builtin_amdgcn_exp2f(x)
#else
#define EXP2(x) exp2f(x)
#endif

__device__ __forceinline__ void gl_lds16(const void* g, void* l) {
  __builtin_amdgcn_global_load_lds(
      (const __attribute__((address_space(1))) unsigned int*)g,
      (__attribute__((address_space(3))) unsigned int*)l, 16, 0, 0);
}

__device__ __forceinline__ float wave_sum(float v) {
#pragma unroll
  for (int o = 1; o < 64; o <<= 1) v += __shfl_xor(v, o);
  return v;
}

// Store one row's 2 consecutive dims (d = lane*2) as i8 into frag-major:
// element (row, d): kk = d>>5 (K-step of 32), sub = (d&31)>>4, j = d&15,
// byte = ((tile*4 + kk)*64 + ((sub<<5)|(row&31)))*16 + j.
__device__ __forceinline__ void store_frag_i8(char* __restrict__ base, int row,
                                              int lane, int bx, int by) {
  const int d = lane * 2;
  const int kk = d >> 5, sub = (d & 31) >> 4, j = d & 15;
  const int tile = row >> 5, lt = (sub << 5) | (row & 31);
  char* dst = base + (((size_t)(tile * 4 + kk) * 64 + lt) * 16 + j);
  dst[0] = (char)bx;
  dst[1] = (char)by;
}

// Prep: X rows -> i8 frag-major (per-row qscale=127/rawmax), scx[n] exp-arg
// scale, exact fp32 pos logit; E rows -> i8 frag-major (normalized, scale 127).
// 4 rows/wave with gathers issued up front (latency ILP). Block 0 zeroes cnt.
__global__ __launch_bounds__(256) void prep_kernel(
    const float* __restrict__ x, const int* __restrict__ tgt,
    const int* __restrict__ nid, const float* __restrict__ proj,
    char* __restrict__ xf, char* __restrict__ ef,
    float* __restrict__ pl, float* __restrict__ scx,
    unsigned int* __restrict__ cnt) {
  if (blockIdx.x == 0 && threadIdx.x == 0) *cnt = 0u;
  const int wave = threadIdx.x >> 6, lane = threadIdx.x & 63;
  if (blockIdx.x < 1024) {
    const int n0 = blockIdx.x * 16 + wave * 4;
    int tg[4];
    float2 xr[4], pr[4];
#pragma unroll
    for (int i = 0; i < 4; ++i) {
      const int t = tgt[n0 + i];
      tg[i] = t < 0 ? 0 : (t > VOCAB - 1 ? VOCAB - 1 : t);
      xr[i] = *reinterpret_cast<const float2*>(x + (size_t)(n0 + i) * D + lane * 2);
    }
#pragma unroll
    for (int i = 0; i < 4; ++i)
      pr[i] = *reinterpret_cast<const float2*>(proj + (size_t)tg[i] * D + lane * 2);
#pragma unroll
    for (int i = 0; i < 4; ++i) {
      float sx = xr[i].x * xr[i].x + xr[i].y * xr[i].y;
      float sp = pr[i].x * pr[i].x + pr[i].y * pr[i].y;
      float dt = xr[i].x * pr[i].x + xr[i].y * pr[i].y;
      float mx = fmaxf(fabsf(xr[i].x), fabsf(xr[i].y));
#pragma unroll
      for (int o = 1; o < 64; o <<= 1) {
        sx += __shfl_xor(sx, o);
        sp += __shfl_xor(sp, o);
        dt += __shfl_xor(dt, o);
        mx = fmaxf(mx, __shfl_xor(mx, o));
      }
      const float norm = sqrtf(sx) + 1e-12f;
      if (lane == 0) {
        pl[n0 + i] = dt / (norm * (sqrtf(sp) + 1e-12f)) * 20.0f;  // /TEMP
        scx[n0 + i] = K1F * (mx + 1e-20f) / (16129.0f * norm);    // 127^2
      }
      const float qs = 127.0f / (mx + 1e-20f);  // raw-domain quant scale
      store_frag_i8(xf, n0 + i, lane, (int)rintf(xr[i].x * qs),
                    (int)rintf(xr[i].y * qs));
    }
  } else {
    const int s0 = (blockIdx.x - 1024) * 16 + wave * 4;
    float2 er[4];
#pragma unroll
    for (int i = 0; i < 4; ++i) {
      const int id = nid[s0 + i];
      er[i] = *reinterpret_cast<const float2*>(proj + (size_t)id * D + lane * 2);
    }
#pragma unroll
    for (int i = 0; i < 4; ++i) {
      const float qs =
          127.0f / (sqrtf(wave_sum(er[i].x * er[i].x + er[i].y * er[i].y)) + 1e-12f);
      store_frag_i8(ef, s0 + i, lane, (int)rintf(er[i].x * qs),
                    (int)rintf(er[i].y * qs));
    }
  }
}

// Flash kernel, i8 F=2, SSPLIT=16: grid 1024 -> 4 blocks/CU (4 waves/SIMD)
// so barrier idles and exp2/ds latencies hide across co-resident blocks.
// Each block: 256 X-cols, 512-s slice in 8 64-s supertiles (8 KB each,
// double-buffered global_load_lds). Exact i32 accum; arg = c * scx[col].
__global__ __launch_bounds__(256, 4) void flash_kernel(
    const char* __restrict__ xf, const char* __restrict__ ef,
    const float* __restrict__ scx, float* __restrict__ psum) {
  __shared__ __align__(16) char lds[2][8192];
  const int tid = threadIdx.x, wave = tid >> 6, lane = tid & 63;
  const int nb = blockIdx.x & 63, ss = blockIdx.x >> 6;
  const int nbase = nb * 256 + wave * 64;

  // B fragments (X): 2 n-frags (64 rows) x 4 k-steps, from frag-major xf.
  i32x4 bq[2][4];
#pragma unroll
  for (int nf = 0; nf < 2; ++nf) {
    const char* p = xf + ((size_t)(nb * 8 + wave * 2 + nf) * 4096) + lane * 16;
#pragma unroll
    for (int kk = 0; kk < 4; ++kk)
      bq[nf][kk] = *reinterpret_cast<const i32x4*>(p + kk * 1024);
  }
  const float scx0 = scx[nbase + (lane & 31)];
  const float scx1 = scx[nbase + 32 + (lane & 31)];

  const char* esrc = ef + (size_t)ss * 65536;  // 512-s slice, 128 B/row
  float acc0 = 0.f, acc1 = 0.f;

  {  // stage supertile 0 (8 KB: 256 threads x 2 x 16 B)
    const char* g = esrc + tid * 16;
    char* l = &lds[0][0] + tid * 16;
    gl_lds16(g, l);
    gl_lds16(g + 4096, l + 4096);
  }
  __syncthreads();

  for (int st = 0; st < 8; ++st) {
    if (st < 7) {  // prefetch next supertile into the other buffer
      const char* g = esrc + (size_t)(st + 1) * 8192 + tid * 16;
      char* l = &lds[(st + 1) & 1][0] + tid * 16;
      gl_lds16(g, l);
      gl_lds16(g + 4096, l + 4096);
    }
    const char* cb = &lds[st & 1][0];
#pragma unroll
    for (int tt = 0; tt < 2; ++tt) {
      i32x16 c0, c1;
#pragma unroll
      for (int r = 0; r < 16; ++r) { c0[r] = 0; c1[r] = 0; }
      const char* ab = cb + tt * 4096 + lane * 16;
#pragma unroll
      for (int kk = 0; kk < 4; ++kk) {
        i32x4 a = *reinterpret_cast<const i32x4*>(ab + kk * 1024);
        c0 = __builtin_amdgcn_mfma_i32_32x32x32_i8(a, bq[0][kk], c0, 0, 0, 0);
        c1 = __builtin_amdgcn_mfma_i32_32x32x32_i8(a, bq[1][kk], c1, 0, 0, 0);
      }
      float e0[16], e1[16];
#pragma unroll
      for (int r = 0; r < 16; ++r) {
        e0[r] = EXP2((float)c0[r] * scx0);
        e1[r] = EXP2((float)c1[r] * scx1);
      }
#pragma unroll
      for (int s2 = 8; s2; s2 >>= 1)
#pragma unroll
        for (int r = 0; r < s2; ++r) { e0[r] += e0[r + s2]; e1[r] += e1[r + s2]; }
      acc0 += e0[0];
      acc1 += e1[0];
    }
    __syncthreads();
  }

  // lanes l and l+32 hold different s-rows of the same column n: combine.
  acc0 += __shfl_xor(acc0, 32);
  acc1 += __shfl_xor(acc1, 32);
  if (lane < 32) {
    psum[(size_t)ss * NROWS + nbase + lane] = acc0;
    psum[(size_t)ss * NROWS + nbase + 32 + lane] = acc1;
  }
}

// Finish (with fused final): 64 blocks x 256 rows. Per-row CE + weighted
// partials; last-arriving block (64 ACQ_REL bumps total) reduces to out[0].
__global__ __launch_bounds__(256) void finish_kernel(
    const float* __restrict__ psum, const float* __restrict__ pl,
    const int* __restrict__ tgt, const float* __restrict__ wts,
    float* __restrict__ fin, unsigned int* __restrict__ cnt,
    float* __restrict__ out) {
  const int n = blockIdx.x * 256 + threadIdx.x;
  float tot = 0.f;
#pragma unroll
  for (int s = 0; s < SSPLIT; ++s) tot += psum[(size_t)s * NROWS + n];
  const float p = pl[n];
  tot += EXP2(p * LOG2EF);             // + exp(pos_logit), unshifted
  const float ce = logf(tot) - p;      // logZ - pos_logit
  const float w = wts[n] * (tgt[n] != -100 ? 1.f : 0.f);
  float a = wave_sum(ce * w);
  float b = wave_sum(w);
  __shared__ float sa[4], sb[4];
  __shared__ int last;
  const int wave = threadIdx.x >> 6, lane = threadIdx.x & 63;
  if (lane == 0) { sa[wave] = a; sb[wave] = b; }
  __syncthreads();
  if (threadIdx.x == 0) {
    __hip_atomic_store(&fin[blockIdx.x * 2], sa[0] + sa[1] + sa[2] + sa[3],
                       __ATOMIC_RELAXED, __HIP_MEMORY_SCOPE_AGENT);
    __hip_atomic_store(&fin[blockIdx.x * 2 + 1], sb[0] + sb[1] + sb[2] + sb[3],
                       __ATOMIC_RELAXED, __HIP_MEMORY_SCOPE_AGENT);
    const unsigned int old = __hip_atomic_fetch_add(cnt, 1u, __ATOMIC_ACQ_REL,
                                                    __HIP_MEMORY_SCOPE_AGENT);
    last = (old == 63u);
  }
  __syncthreads();
  if (last && threadIdx.x < 64) {  // wave 0 of last block reduces 64 pairs
    const float A = wave_sum(__hip_atomic_load(&fin[threadIdx.x * 2],
                                               __ATOMIC_RELAXED,
                                               __HIP_MEMORY_SCOPE_AGENT));
    const float B = wave_sum(__hip_atomic_load(&fin[threadIdx.x * 2 + 1],
                                               __ATOMIC_RELAXED,
                                               __HIP_MEMORY_SCOPE_AGENT));
    if (threadIdx.x == 0) out[0] = A / fmaxf(B, 1e-12f);
  }
}

extern "C" void kernel_launch(void* const* d_in, const int* in_sizes, int n_in,
                              void* d_out, int out_size, void* d_ws, size_t ws_size,
                              hipStream_t stream) {
  const float* x    = (const float*)d_in[0];
  const int*   tgt  = (const int*)d_in[1];
  const int*   nid  = (const int*)d_in[2];
  const float* wts  = (const float*)d_in[3];
  const float* proj = (const float*)d_in[4];
  float* out = (float*)d_out;
  char* ws = (char*)d_ws;
  char* xf = ws + XF_OFF;
  char* ef = ws + EF_OFF;
  float* pl   = (float*)(ws + PL_OFF);
  float* scx  = (float*)(ws + SCX_OFF);
  float* psum = (float*)(ws + PS_OFF);
  float* fin  = (float*)(ws + FP_OFF);
  unsigned int* cnt = (unsigned int*)(ws + CNT_OFF);

  hipLaunchKernelGGL(prep_kernel, dim3(1024 + 512), dim3(256), 0, stream,
                     x, tgt, nid, proj, xf, ef, pl, scx, cnt);
  hipLaunchKernelGGL(flash_kernel, dim3(64 * SSPLIT), dim3(256), 0, stream,
                     xf, ef, scx, psum);
  hipLaunchKernelGGL(finish_kernel, dim3(NROWS / 256), dim3(256), 0, stream,
                     psum, pl, tgt, wts, fin, cnt, out);
}